// Round 11
// baseline (2831.076 us; speedup 1.0000x reference)
//
#include <hip/hip_runtime.h>
#include <math.h>

#define NHID    1024
#define NSTEP   512
#define NB      32
#define NSPLIT  8
#define THREADS 512
#define NWAVES  8
#define NWORD   64    // 16-bit fragments per batch (one per publishing wave)

typedef int v4i __attribute__((vector_size(16)));

// 256 blocks = 32 batches x 8 splits (1 block/CU, XCD=blk%8 heuristic),
// 8 waves each. Wave owns 16 columns end-to-end (lane = slot(row-phase) x
// col): gathers ALL spiking rows for its cols (4 rows/instr), combines
// slots via 2 commutative shfl_xor (bitwise-identical in every lane), runs
// elementwise redundantly (4 copies), publishes its 16-bit spike fragment
// as ONE tagged u64 (tag<<32|frag, relaxed agent store, own 64B line).
// NO barriers, NO LDS combine in the loop. Poll: lane L polls word L of its
// batch (64 parallel lines). Expand: 16-bit-window scan, redundant per wave.
// Gather chunks: r9-proven 16 asm buffer_loads + vmcnt(0) drain +
// sched_barrier (<=16 live asm outputs -> no spill risk). Sentinel rows are
// SRD-OOB -> hardware returns 0.0 (+0.0f exact). Elementwise math in exact
// reference order, contraction off.
__global__ __launch_bounds__(THREADS, 1)
void coesn_kernel(const float* __restrict__ x,
                  const float* __restrict__ x2h,
                  const float* __restrict__ h2h,
                  const float* __restrict__ bias,
                  const float* __restrict__ gamma_,
                  const float* __restrict__ eps_,
                  float* __restrict__ out,
                  unsigned long long* __restrict__ masks,
                  int ws64s,                 // u64 stride per word (8=padded)
                  float ref_decay)
{
#pragma clang fp contract(off)
    const int tid  = threadIdx.x;
    const int blk  = blockIdx.x;
    const int b    = blk >> 3;      // batch
    const int j    = blk & 7;       // split (XCD j heuristic)
    const int w    = tid >> 6;      // wave 0..7
    const int lane = tid & 63;
    const int slot = lane >> 4;     // row phase 0..3
    const int c    = lane & 15;     // col within wave's 16

    __shared__ float xs[NSTEP];
    __shared__ int offl[NWAVES][NHID + 64];   // per-wave row byte-offsets

    xs[tid] = x[b * NSTEP + tid];
    __syncthreads();                // once, before the loop

    const int col = j * 128 + w * 16 + c;
    const float w_in = x2h[col];
    const float bi   = bias[col];
    const float ga   = gamma_[col];
    const float ep   = eps_[col];

    // SRD over h2h shifted by this split's column base (j*512 bytes)
    union { const float* p; unsigned u[2]; } cv; cv.p = h2h + j * 128;
    v4i srd = { (int)cv.u[0], (int)(cv.u[1] & 0xffffu),
                (int)(NHID * NHID * 4 - j * 512), 0x00020000 };
    const int lanecol = (w * 16 + c) << 2;    // byte offset within row slice

    int* offw = offl[w];

    float hy = 0.f, hz = 0.f, ref = 0.f, lv = 0.f;
    int scount = 0;

    for (int t = 0; t < NSTEP; ++t) {
        int total = 0, npad = 0;

        if (t > 0) {
            const int rpar = (t - 1) & 1;
            const unsigned long long* ap =
                masks + ((size_t)(rpar * NB + b) * NWORD + lane) * ws64s;
            unsigned long long v;
            int spin = 0;
            for (;;) {
                v = __hip_atomic_load(ap, __ATOMIC_RELAXED,
                                      __HIP_MEMORY_SCOPE_AGENT);
                if ((unsigned)(v >> 32) == (unsigned)t) break;
                __builtin_amdgcn_s_sleep(1);
                if (((++spin) & 1023) == 0)          // cold escape hatch
                    (void)__hip_atomic_load(ap, __ATOMIC_ACQUIRE,
                                            __HIP_MEMORY_SCOPE_AGENT);
            }
            // ---- expand: lane's 16-bit window = neurons [16*lane, +16) ----
            unsigned bits = (unsigned)v & 0xFFFFu;
            int pc  = __popc(bits);
            int inc = pc;
            #pragma unroll
            for (int d = 1; d < 64; d <<= 1) {
                int y = __shfl_up(inc, d, 64);
                if (lane >= d) inc += y;
            }
            total = __shfl(inc, 63, 64);
            int off = inc - pc;
            const int rbase = lane << 4;
            unsigned bb = bits;
            while (bb) {
                int bit = __builtin_ctz(bb); bb &= bb - 1u;
                offw[off++] = (rbase + bit) << 12;   // row*4096 bytes
            }
            npad = (total + 63) & ~63;
            if (total + lane < npad)
                offw[total + lane] = NHID << 12;     // OOB sentinel -> 0.0
        }

        // ---- gather: 64 positions/chunk (16 instrs x 4 row-slots) ----
        float acc = 0.f;
        for (int k = 0; k < npad; k += 64) {
            int ro[16];
            #pragma unroll
            for (int i = 0; i < 16; ++i)
                ro[i] = offw[k + 4 * i + slot];      // LDS, 4-way broadcast
            float vv[16];
            #pragma unroll
            for (int i = 0; i < 16; ++i)
                asm volatile("buffer_load_dword %0, %1, %2, 0 offen"
                             : "=v"(vv[i]) : "v"(ro[i] + lanecol), "s"(srd));
            asm volatile("s_waitcnt vmcnt(0)" ::: "memory");
            __builtin_amdgcn_sched_barrier(0);
            #pragma unroll
            for (int i = 0; i < 16; ++i) acc += vv[i];   // ascending chain
        }
        // cross-slot tree: commutative pairs -> bitwise identical all lanes
        float o16 = __shfl_xor(acc, 16, 64);
        acc = acc + o16;
        float o32 = __shfl_xor(acc, 32, 64);
        acc = acc + o32;

        // ---- LIF (exact reference expression order, no FMA) ----
        float xv  = xs[t];
        float pp  = xv * w_in;
        float q   = pp + acc;
        float cur = q + bi;

        float aa = (-lv) / 20.0f;
        float bb2 = aa + cur;
        lv = lv + 0.042f * bb2;
        float ls = (lv > 0.05f) ? 1.0f : 0.0f;
        lv = lv - ls * 0.05f;

        // ---- HRF oscillator ----
        float t1 = 35.0f * ls;
        float t2 = ga * hy;
        float t3 = ep * hz;
        float t4 = (t1 - t2) - t3;
        hz = hz + 0.042f * t4;
        hy = hy + 0.042f * hz;

        float sv = (hy - 0.05f) - ref;
        int sp = (sv > 0.0f) ? 1 : 0;
        ref = ref * ref_decay + (sp ? 1.0f : 0.0f);
        scount += sp;

        // ---- publish this wave's 16-bit fragment (one tagged u64) ----
        unsigned long long bal = __ballot(sp);       // replicated 16b pattern
        if (t < NSTEP - 1 && lane == 0) {
            unsigned long long payload =
                (((unsigned long long)(t + 1)) << 32) |
                (unsigned)(bal & 0xFFFFull);
            __hip_atomic_store(
                masks + ((size_t)((t & 1) * NB + b) * NWORD + (j * 8 + w)) * ws64s,
                payload, __ATOMIC_RELAXED, __HIP_MEMORY_SCOPE_AGENT);
        }
    }

    if (lane < 16)
        out[b * NHID + j * 128 + w * 16 + lane] =
            (float)scount * (1.0f / 512.0f);
}

extern "C" void kernel_launch(void* const* d_in, const int* in_sizes, int n_in,
                              void* d_out, int out_size, void* d_ws, size_t ws_size,
                              hipStream_t stream) {
    const float* x     = (const float*)d_in[0];
    const float* x2h   = (const float*)d_in[1];
    const float* h2h   = (const float*)d_in[2];
    const float* bias  = (const float*)d_in[3];
    const float* gamma = (const float*)d_in[4];
    const float* eps   = (const float*)d_in[5];
    float* out = (float*)d_out;

    // masks: [2][NB][NWORD] tagged u64 words, each padded to its own 64B
    // line when ws allows (kills L3 line-level atomic serialization).
    int ws64s = (ws_size >= 262144) ? 8 : 1;
    size_t msz = (size_t)2 * NB * NWORD * 8 * ws64s;
    unsigned long long* masks = (unsigned long long*)d_ws;
    hipMemsetAsync(d_ws, 0, msz, stream);

    float ref_decay = (float)exp(-(0.042 / 0.25));

    coesn_kernel<<<NB * NSPLIT, THREADS, 0, stream>>>(
        x, x2h, h2h, bias, gamma, eps, out, masks, ws64s, ref_decay);
}

// Round 13
// 2461.004 us; speedup vs baseline: 1.1504x; 1.1504x over previous
//
#include <hip/hip_runtime.h>
#include <math.h>

#define NHID    1024
#define NSTEP   512
#define NB      32
#define NSPLIT  8
#define THREADS 512
#define NWAVES  8

typedef float f2 __attribute__((ext_vector_type(2)));
typedef int  v4i __attribute__((vector_size(16)));

// 256 blocks = 32 batches x 8 column-splits, 8 waves each (1 block/CU).
// Exchange is tagged u32 words: (tag<<16)|16 spike bits; 64 words per batch
// per parity, packed in 8 lines total. Wave w gathers rows [128w,128w+128):
// it polls its 8 words with ONE 8-lane relaxed agent load per iteration
// (one cache line), throttled by s_sleep(2) -> poll traffic ~8-30x lower
// than r8/r9 (whose fabric contention was the 3.5us/step residual).
// Publishes: 8 single u32 atomic stores per block. Gather: r9-proven
// 16-deep buffer_load_dwordx2 chunks + vmcnt(0) drain (sentinels SRD-OOB
// -> 0.0). One barrier/step, parity-double-buffered partials, ascending
// row/wave summation (round-1 numerics class). Elementwise math in exact
// reference order, contraction off.
__global__ __launch_bounds__(THREADS, 1)
void coesn_kernel(const float* __restrict__ x,
                  const float* __restrict__ x2h,
                  const float* __restrict__ h2h,
                  const float* __restrict__ bias,
                  const float* __restrict__ gamma_,
                  const float* __restrict__ eps_,
                  float* __restrict__ out,
                  unsigned int* __restrict__ masks,   // [NB][2][64] u32
                  float ref_decay)
{
#pragma clang fp contract(off)
    const int tid  = threadIdx.x;
    const int blk  = blockIdx.x;
    const int b    = blk & 31;      // batch
    const int j    = blk >> 5;      // column split
    const int w    = tid >> 6;      // wave 0..7 (owns rows [128w,128w+128))
    const int lane = tid & 63;

    __shared__ float xs[NSTEP];
    __shared__ int   idxs[NWAVES][144];      // per-wave row byte-offsets
    __shared__ float part[2][NWAVES][128];   // parity-buffered partials

    for (int i = tid; i < NSTEP; i += THREADS) xs[i] = x[b * NSTEP + i];

    float w_in = 0.f, bi = 0.f, ga = 0.f, ep = 0.f;
    if (tid < 128) {
        int col = j * 128 + tid;
        w_in = x2h[col]; bi = bias[col]; ga = gamma_[col]; ep = eps_[col];
    }

    // SRD over h2h: num_records = 4 MB -> sentinel row 1024 is OOB -> 0.0
    union { const float* p; unsigned u[2]; } cv; cv.p = h2h;
    v4i srd = { (int)cv.u[0], (int)(cv.u[1] & 0xffffu),
                (int)(NHID * NHID * 4), 0x00020000 };
    const int cbase = j * 512 + lane * 8;    // lane's col-pair byte offset

    int* offw = idxs[w];

    float hy = 0.f, hz = 0.f, ref = 0.f, lv = 0.f;
    int scount = 0;

    __syncthreads();

    for (int t = 0; t < NSTEP; ++t) {
        const int par = t & 1;
        int npad = 0;

        if (t > 0) {
            // ---- poll: lanes 0..7 read words 8w..8w+7 (one line) ----
            unsigned v = 0;
            if (lane < 8) {
                const unsigned* ap =
                    masks + ((b * 2 + par) << 6) + (w << 3) + lane;
                int spin = 0;
                for (;;) {
                    v = __hip_atomic_load(ap, __ATOMIC_RELAXED,
                                          __HIP_MEMORY_SCOPE_AGENT);
                    if ((v >> 16) == (unsigned)t) break;
                    __builtin_amdgcn_s_sleep(2);     // throttle poll traffic
                    if (((++spin) & 1023) == 0)      // cold escape hatch
                        (void)__hip_atomic_load(ap, __ATOMIC_ACQUIRE,
                                                __HIP_MEMORY_SCOPE_AGENT);
                }
            }
            // ---- expand: lane covers fragment bits 2*lane, 2*lane+1 ----
            unsigned word = (unsigned)__shfl((int)v, lane >> 3, 64);
            unsigned bits = (word >> ((lane & 7) << 1)) & 3u;
            int pc  = (int)((bits & 1u) + (bits >> 1));
            int inc = pc;
            #pragma unroll
            for (int d = 1; d < 64; d <<= 1) {
                int y = __shfl_up(inc, d, 64);
                if (lane >= d) inc += y;
            }
            int total = __shfl(inc, 63, 64);
            int off   = inc - pc;
            int row0  = (w << 7) + (lane << 1);      // rows 128w+2L, +1
            if (bits & 1u) offw[off] = row0 << 12;
            if (bits & 2u) offw[off + (int)(bits & 1u)] = (row0 + 1) << 12;
            npad = (total + 15) & ~15;
            if (lane < npad - total)
                offw[total + lane] = NHID << 12;     // OOB sentinel -> 0.0
        }

        // ---- gather: 16-deep chunks, vmcnt(0) drain, ordered adds ----
        float ax = 0.f, ay = 0.f;
        for (int k = 0; k < npad; k += 16) {
            int ro[16];
            #pragma unroll
            for (int i = 0; i < 16; ++i) ro[i] = offw[k + i];  // broadcast
            f2 vv[16];
            #pragma unroll
            for (int i = 0; i < 16; ++i)
                asm volatile("buffer_load_dwordx2 %0, %1, %2, 0 offen"
                             : "=v"(vv[i]) : "v"(ro[i] + cbase), "s"(srd));
            asm volatile("s_waitcnt vmcnt(0)" ::: "memory");
            __builtin_amdgcn_sched_barrier(0);
            #pragma unroll
            for (int i = 0; i < 16; ++i) { ax += vv[i].x; ay += vv[i].y; }
        }
        *(f2*)&part[par][w][lane << 1] = (f2){ax, ay};
        __syncthreads();                 // the ONE barrier per step

        if (tid < 128) {
            float rsum = 0.f;
            #pragma unroll
            for (int ww = 0; ww < NWAVES; ++ww) rsum += part[par][ww][tid];

            // ---- LIF (exact reference expression order, no FMA) ----
            float xv  = xs[t];
            float pp  = xv * w_in;
            float q   = pp + rsum;
            float cur = q + bi;

            float aa = (-lv) / 20.0f;
            float bb2 = aa + cur;
            lv = lv + 0.042f * bb2;
            float ls = (lv > 0.05f) ? 1.0f : 0.0f;
            lv = lv - ls * 0.05f;

            // ---- HRF oscillator ----
            float t1 = 35.0f * ls;
            float t2 = ga * hy;
            float t3 = ep * hz;
            float t4 = (t1 - t2) - t3;
            hz = hz + 0.042f * t4;
            hy = hy + 0.042f * hz;

            float sv = (hy - 0.05f) - ref;
            int sp = (sv > 0.0f) ? 1 : 0;
            ref = ref * ref_decay + (sp ? 1.0f : 0.0f);
            scount += sp;

            // ---- publish: 8 tagged u32 stores (relaxed agent) ----
            if (t < NSTEP - 1) {
                unsigned long long bal = __ballot(sp);
                if ((tid & 15) == 0) {
                    int f = j * 8 + (tid >> 4);
                    unsigned data =
                        (unsigned)((bal >> (lane & 48)) & 0xFFFFull);
                    unsigned payload = (((unsigned)(t + 1)) << 16) | data;
                    __hip_atomic_store(
                        masks + ((b * 2 + ((t + 1) & 1)) << 6) + f,
                        payload, __ATOMIC_RELAXED, __HIP_MEMORY_SCOPE_AGENT);
                }
            }
        }
    }

    if (tid < 128)
        out[b * NHID + j * 128 + tid] = (float)scount * (1.0f / 512.0f);
}

extern "C" void kernel_launch(void* const* d_in, const int* in_sizes, int n_in,
                              void* d_out, int out_size, void* d_ws, size_t ws_size,
                              hipStream_t stream) {
    const float* x     = (const float*)d_in[0];
    const float* x2h   = (const float*)d_in[1];
    const float* h2h   = (const float*)d_in[2];
    const float* bias  = (const float*)d_in[3];
    const float* gamma = (const float*)d_in[4];
    const float* eps   = (const float*)d_in[5];
    float* out = (float*)d_out;

    // ws: [0,16384) u32 masks[NB][2][64]  (tag 0 = "not yet published")
    unsigned int* masks = (unsigned int*)d_ws;
    hipMemsetAsync(d_ws, 0, 16384, stream);

    float ref_decay = (float)exp(-(0.042 / 0.25));

    coesn_kernel<<<NB * NSPLIT, THREADS, 0, stream>>>(
        x, x2h, h2h, bias, gamma, eps, out, masks, ref_decay);
}